// Round 1
// baseline (2349.061 us; speedup 1.0000x reference)
//
#include <hip/hip_runtime.h>
#include <hip/hip_bf16.h>

#define NBLK 256
#define NTHR 512
#define MTILE 32
#define KPAD 552              // row stride (elements); 552*2=1104 B, 16B aligned, breaks bank pow2
#define LSTRIDE (128*17*512)  // packed elements per LSTM = 1,114,112

typedef __attribute__((ext_vector_type(8))) short short8;
typedef __attribute__((ext_vector_type(4))) float floatx4;

__device__ inline unsigned short f2bf(float x){
    unsigned u = __float_as_uint(x);
    return (unsigned short)((u + 0x7fffu + ((u>>16)&1u)) >> 16);
}
__device__ inline float bf2f(unsigned short v){
    return __uint_as_float(((unsigned)v)<<16);
}
__device__ inline float sigf(float x){ return 1.f/(1.f+__expf(-x)); }
__device__ inline float tanh_(float x){
    float e = __expf(-2.f*fabsf(x));
    float t = (1.f-e)/(1.f+e);
    return x < 0.f ? -t : t;
}

// Pack W into bf16 fragment-order: BP[ntile(128)][kt(17)][lane(64)][8],
// element = B[k = kt*32 + (lane>>4)*8 + j][n = ntile*16 + (lane&15)]
// where packed n: chunk=n>>7, gate=(n>>5)&3, u=n&31, orig row = gate*512 + chunk*32 + u.
// K rows: 0..511 = W_hh, 512..515 = W_ih, 516 = b_ih+b_hh, 517..543 = 0.
__global__ void prepack(const float* __restrict__ Wih, const float* __restrict__ Whh,
                        const float* __restrict__ bih, const float* __restrict__ bhh,
                        unsigned short* __restrict__ dst)
{
    int f = blockIdx.x*256 + threadIdx.x;
    if (f >= LSTRIDE) return;
    int j    = f & 7;
    int lane = (f>>3) & 63;
    int t2   = f >> 9;
    int kt   = t2 % 17;
    int nt   = t2 / 17;
    int n = nt*16 + (lane&15);
    int k = kt*32 + ((lane>>4)<<3) + j;
    int ch = n>>7, g = (n>>5)&3, u = n&31;
    int row = g*512 + ch*32 + u;
    float v = 0.f;
    if (k < 512)       v = Whh[row*512 + k];
    else if (k < 516)  v = Wih[row*4 + (k-512)];
    else if (k == 516) v = bih[row] + bhh[row];
    dst[f] = f2bf(v);
}

__global__ __launch_bounds__(NTHR, 1)
void lstm_all(const float* __restrict__ speed, const float* __restrict__ pos,
              const unsigned short* __restrict__ wpack,
              const float* __restrict__ wfc, const float* __restrict__ bfc,
              const float* __restrict__ wemb, const float* __restrict__ bemb,
              float* __restrict__ out)
{
    __shared__ __align__(16) unsigned short abuf[2][MTILE][KPAD]; // 70656 B
    __shared__ float smallw[1040];
    __shared__ float partial[NTHR];

    const int tid  = threadIdx.x;
    const int lane = tid & 63;
    const int wv   = tid >> 6;      // wave 0..7 -> hidden [wv*64, wv*64+64)
    const int row0 = blockIdx.x * MTILE;
    const int l15  = lane & 15;
    const int lq   = lane >> 4;

    // ---- init LDS ----
    {
        unsigned* p = (unsigned*)&abuf[0][0][0];
        for (int i = tid; i < 2*MTILE*KPAD/2; i += NTHR) p[i] = 0u;
        for (int i = tid; i < 1024; i += NTHR) smallw[i] = wfc[i];
        if (tid < 2) smallw[1024+tid] = bfc[tid];
        if (tid < 8) smallw[1026+tid] = wemb[tid];
        if (tid < 4) smallw[1034+tid] = bemb[tid];
    }
    __syncthreads();
    if (tid < 64) { int b = tid>>5, m = tid&31; abuf[b][m][516] = 0x3F80; } // bias one = bf16(1.0)
    if (tid < 128) {                                                        // x_speed[t=0] -> buf0
        int m = tid>>2, f3 = tid&3;
        abuf[0][m][512+f3] = f2bf(speed[((size_t)(row0+m)*16 + 0)*4 + f3]);
    }
    __syncthreads();

    float c[32], sh[32], sc[32];
    #pragma unroll
    for (int i = 0; i < 32; ++i) c[i] = 0.f;

    // One LSTM cell step: gates MFMA from abuf[rb] (K=544 incl. x+bias), cell update,
    // h_new (bf16) -> abuf[wbuf]. c stays in registers.
    auto lstm_step = [&](int rb, int wbuf, const unsigned short* base) {
        #pragma unroll 1
        for (int s = 0; s < 2; ++s) {
            const int chunk = 2*wv + s;       // 32-hidden chunk = 128 packed gate cols
            floatx4 acc[2][8];
            #pragma unroll
            for (int a = 0; a < 2; ++a)
                #pragma unroll
                for (int b = 0; b < 8; ++b) acc[a][b] = (floatx4){0.f,0.f,0.f,0.f};
            const unsigned short* bp = base + (size_t)chunk*8*17*512 + lane*8;
            #pragma unroll 1
            for (int kt = 0; kt < 17; ++kt) {
                short8 a0 = *(const short8*)&abuf[rb][l15][kt*32 + lq*8];
                short8 a1 = *(const short8*)&abuf[rb][16 + l15][kt*32 + lq*8];
                short8 bfr[8];
                #pragma unroll
                for (int nt = 0; nt < 8; ++nt)
                    bfr[nt] = *(const short8*)(bp + nt*(17*512) + kt*512);
                #pragma unroll
                for (int nt = 0; nt < 8; ++nt) {
                    acc[0][nt] = __builtin_amdgcn_mfma_f32_16x16x32_bf16(a0, bfr[nt], acc[0][nt], 0,0,0);
                    acc[1][nt] = __builtin_amdgcn_mfma_f32_16x16x32_bf16(a1, bfr[nt], acc[1][nt], 0,0,0);
                }
            }
            // ntile pairs: 0..1=i, 2..3=f, 4..5=g, 6..7=o (upos = ntile&1)
            #pragma unroll
            for (int mf = 0; mf < 2; ++mf)
                #pragma unroll
                for (int up = 0; up < 2; ++up)
                    #pragma unroll
                    for (int r = 0; r < 4; ++r) {
                        int ci = ((s*2+up)*2+mf)*4 + r;
                        float gi = acc[mf][0+up][r];
                        float gf = acc[mf][2+up][r];
                        float gg = acc[mf][4+up][r];
                        float go = acc[mf][6+up][r];
                        float cn = sigf(gf)*c[ci] + sigf(gi)*tanh_(gg);
                        c[ci] = cn;
                        float h = sigf(go)*tanh_(cn);
                        int m = mf*16 + lq*4 + r;
                        int u = chunk*32 + up*16 + l15;
                        abuf[wbuf][m][u] = f2bf(h);
                    }
        }
    };

    const unsigned short* wsp = wpack;
    const unsigned short* wpp = wpack + LSTRIDE;
    const unsigned short* wdp = wpack + 2*(size_t)LSTRIDE;

    // ---- speed encoder ----
    #pragma unroll 1
    for (int t = 0; t < 16; ++t) {
        lstm_step(t&1, (t+1)&1, wsp);
        if (t < 15 && tid < 128) {
            int m = tid>>2, f3 = tid&3;
            abuf[(t+1)&1][m][512+f3] = f2bf(speed[((size_t)(row0+m)*16 + t+1)*4 + f3]);
        }
        __syncthreads();
    }
    // save sh (from abuf[0]) and sc; reset c
    #pragma unroll
    for (int s = 0; s < 2; ++s)
        #pragma unroll
        for (int mf = 0; mf < 2; ++mf)
            #pragma unroll
            for (int up = 0; up < 2; ++up)
                #pragma unroll
                for (int r = 0; r < 4; ++r) {
                    int ci = ((s*2+up)*2+mf)*4 + r;
                    int m = mf*16 + lq*4 + r;
                    int u = (2*wv+s)*32 + up*16 + l15;
                    sh[ci] = bf2f(abuf[0][m][u]);
                    sc[ci] = c[ci];
                    c[ci]  = 0.f;
                }
    __syncthreads();
    // zero buf0 h-region; load x_pos[0]
    for (int i = tid; i < MTILE*256; i += NTHR) {
        int m = i>>8, kk = i&255;
        ((unsigned*)&abuf[0][m][0])[kk] = 0u;
    }
    if (tid < 128) {
        int m = tid>>2, f3 = tid&3;
        abuf[0][m][512+f3] = f2bf(pos[((size_t)(row0+m)*16 + 0)*4 + f3]);
    }
    __syncthreads();

    // ---- pos encoder ----
    #pragma unroll 1
    for (int t = 0; t < 16; ++t) {
        lstm_step(t&1, (t+1)&1, wpp);
        if (t < 15 && tid < 128) {
            int m = tid>>2, f3 = tid&3;
            abuf[(t+1)&1][m][512+f3] = f2bf(pos[((size_t)(row0+m)*16 + t+1)*4 + f3]);
        }
        __syncthreads();
    }
    // h0 = ph + sh (in place in abuf[0]); c0 = pc + sc; last_pos0 = pos[:,15,:]
    #pragma unroll
    for (int s = 0; s < 2; ++s)
        #pragma unroll
        for (int mf = 0; mf < 2; ++mf)
            #pragma unroll
            for (int up = 0; up < 2; ++up)
                #pragma unroll
                for (int r = 0; r < 4; ++r) {
                    int ci = ((s*2+up)*2+mf)*4 + r;
                    int m = mf*16 + lq*4 + r;
                    int u = (2*wv+s)*32 + up*16 + l15;
                    abuf[0][m][u] = f2bf(bf2f(abuf[0][m][u]) + sh[ci]);
                    c[ci] += sc[ci];
                }
    if (tid < 128) {
        int m = tid>>2, f3 = tid&3;
        abuf[0][m][512+f3] = f2bf(pos[((size_t)(row0+m)*16 + 15)*4 + f3]);
    }
    __syncthreads();

    // ---- decoder ----
    #pragma unroll 1
    for (int t = 0; t < 16; ++t) {
        int rb = t&1, wbuf = (t+1)&1;
        lstm_step(rb, wbuf, wdp);
        __syncthreads();
        // crossing partials: wave wv covers k-slice [wv*64, wv*64+64); lane -> (row=lane>>1, col=lane&1)
        {
            int r = lane>>1, col = lane&1;
            const unsigned short* hp = &abuf[wbuf][r][wv*64];
            const float* wp = &smallw[col*512 + wv*64];
            float p = 0.f;
            #pragma unroll
            for (int k = 0; k < 64; ++k) p += bf2f(hp[k]) * wp[k];
            partial[wv*64 + lane] = p;
        }
        __syncthreads();
        if (wv == 0) {
            float p = 0.f;
            #pragma unroll
            for (int i = 0; i < 8; ++i) p += partial[i*64 + lane];
            int r = lane>>1, col = lane&1;
            p += smallw[1024+col];
            float cr = fmaxf(p, 0.f);                       // crossing (post-relu)
            float other = __shfl_xor(cr, 1, 64);
            float mx = fmaxf(cr, other);
            float e0 = __expf(cr-mx), e1 = __expf(other-mx);
            out[((size_t)(row0+r))*32 + t*2 + col] = e0/(e0+e1);  // softmax
            float c0v = col ? other : cr;
            float c1v = col ? cr : other;
            #pragma unroll
            for (int q = 0; q < 2; ++q) {                   // last_pos = relu(crossing@Wemb^T + bemb)
                int e = col*2 + q;
                float lp = fmaxf(c0v*smallw[1026+e*2] + c1v*smallw[1026+e*2+1] + smallw[1034+e], 0.f);
                abuf[wbuf][r][512+e] = f2bf(lp);
            }
        }
        __syncthreads();
    }
}

extern "C" void kernel_launch(void* const* d_in, const int* in_sizes, int n_in,
                              void* d_out, int out_size, void* d_ws, size_t ws_size,
                              hipStream_t stream)
{
    (void)in_sizes; (void)n_in; (void)out_size; (void)ws_size;
    const float* speed = (const float*)d_in[0];
    const float* pos   = (const float*)d_in[1];
    const float* Ws_ih = (const float*)d_in[2];
    const float* Ws_hh = (const float*)d_in[3];
    const float* bs_ih = (const float*)d_in[4];
    const float* bs_hh = (const float*)d_in[5];
    const float* Wp_ih = (const float*)d_in[6];
    const float* Wp_hh = (const float*)d_in[7];
    const float* bp_ih = (const float*)d_in[8];
    const float* bp_hh = (const float*)d_in[9];
    const float* Wd_ih = (const float*)d_in[10];
    const float* Wd_hh = (const float*)d_in[11];
    const float* bd_ih = (const float*)d_in[12];
    const float* bd_hh = (const float*)d_in[13];
    const float* W_fc  = (const float*)d_in[14];
    const float* b_fc  = (const float*)d_in[15];
    const float* W_emb = (const float*)d_in[16];
    const float* b_emb = (const float*)d_in[17];

    unsigned short* wp = (unsigned short*)d_ws;
    int gb = (LSTRIDE + 255) / 256;
    prepack<<<gb, 256, 0, stream>>>(Ws_ih, Ws_hh, bs_ih, bs_hh, wp);
    prepack<<<gb, 256, 0, stream>>>(Wp_ih, Wp_hh, bp_ih, bp_hh, wp + LSTRIDE);
    prepack<<<gb, 256, 0, stream>>>(Wd_ih, Wd_hh, bd_ih, bd_hh, wp + 2*(size_t)LSTRIDE);
    lstm_all<<<NBLK, NTHR, 0, stream>>>(speed, pos, wp, W_fc, b_fc, W_emb, b_emb, (float*)d_out);
}

// Round 3
// 1189.119 us; speedup vs baseline: 1.9755x; 1.9755x over previous
//
#include <hip/hip_runtime.h>
#include <hip/hip_bf16.h>

#define NBLK 256
#define NTHR 512
#define MTILE 32
#define KPAD 552                 // abuf row stride (elements)
#define CHELEM (17*8*512)        // packed elements per 16-col chunk = 69632
#define LSTRIDE (16*CHELEM)      // packed elements per LSTM = 1,114,112

typedef __attribute__((ext_vector_type(8))) short short8;
typedef __attribute__((ext_vector_type(4))) float floatx4;

__device__ inline unsigned short f2bf(float x){
    unsigned u = __float_as_uint(x);
    return (unsigned short)((u + 0x7fffu + ((u>>16)&1u)) >> 16);
}
__device__ inline float bf2f(unsigned short v){ return __uint_as_float(((unsigned)v)<<16); }
__device__ inline float ex2(float x){ return __builtin_amdgcn_exp2f(x); }
// rcp with one Newton iteration: near-exact fp32 reciprocal at 3 VALU ops
__device__ inline float rcpn(float d){
    float r = __builtin_amdgcn_rcpf(d);
    return r * (2.f - d*r);
}
#define LOG2E 1.4426950408889634f
__device__ inline float sigf(float x){ return rcpn(1.f + ex2(-LOG2E*x)); }
__device__ inline float tanh_(float x){ return 2.f*rcpn(1.f + ex2(-2.f*LOG2E*x)) - 1.f; }

// Packed layout: BP[chunk(16)][kt(17)][nt(8)][lane(64)][8]
// element = B[k][n], n = (chunk*8+nt)*16 + (lane&15), k = kt*32 + (lane>>4)*8 + j
// packed n decode: ch=n>>7, gate=(n>>5)&3, u=n&31 -> orig row = gate*512 + ch*32 + u
// K rows: 0..511 = W_hh, 512..515 = W_ih, 516 = b_ih+b_hh, 517..543 = 0
__global__ void prepack(const float* __restrict__ Wih, const float* __restrict__ Whh,
                        const float* __restrict__ bih, const float* __restrict__ bhh,
                        unsigned short* __restrict__ dst)
{
    int f = blockIdx.x*256 + threadIdx.x;
    if (f >= LSTRIDE) return;
    int j    = f & 7;
    int lane = (f>>3) & 63;
    int nt   = (f>>9) & 7;
    int rem  = f >> 12;
    int kt   = rem % 17;
    int chunk= rem / 17;
    int n = (chunk*8 + nt)*16 + (lane&15);
    int k = kt*32 + ((lane>>4)<<3) + j;
    int ch = n>>7, g = (n>>5)&3, u = n&31;
    int row = g*512 + ch*32 + u;
    float v = 0.f;
    if (k < 512)       v = Whh[row*512 + k];
    else if (k < 516)  v = Wih[row*4 + (k-512)];
    else if (k == 516) v = bih[row] + bhh[row];
    dst[f] = f2bf(v);
}

__global__ __launch_bounds__(NTHR, 2)
void lstm_all(const float* __restrict__ speed, const float* __restrict__ pos,
              const unsigned short* __restrict__ wpack,
              const float* __restrict__ wfc, const float* __restrict__ bfc,
              const float* __restrict__ wemb, const float* __restrict__ bemb,
              float* __restrict__ out)
{
    __shared__ __align__(16) unsigned short abuf[2][MTILE][KPAD];   // 70656 B
    __shared__ __align__(16) unsigned short hsave[MTILE][512];      // 32768 B
    __shared__ float smallw[1040];
    __shared__ float partial[NTHR];

    const int tid  = threadIdx.x;
    const int lane = tid & 63;
    const int wv   = tid >> 6;
    const int row0 = blockIdx.x * MTILE;
    const int l15  = lane & 15;
    const int lq   = lane >> 4;

    // ---- init LDS ----
    {
        unsigned* p = (unsigned*)&abuf[0][0][0];
        for (int i = tid; i < 2*MTILE*KPAD/2; i += NTHR) p[i] = 0u;
        for (int i = tid; i < 1024; i += NTHR) smallw[i] = wfc[i];
        if (tid < 2) smallw[1024+tid] = bfc[tid];
        if (tid < 8) smallw[1026+tid] = wemb[tid];
        if (tid < 4) smallw[1034+tid] = bemb[tid];
    }
    __syncthreads();
    if (tid < 64) { int b = tid>>5, m = tid&31; abuf[b][m][516] = 0x3F80; } // bias-one
    if (tid < 128) {
        int m = tid>>2, f3 = tid&3;
        abuf[0][m][512+f3] = f2bf(speed[((size_t)(row0+m)*16 + 0)*4 + f3]);
    }
    __syncthreads();

    float c0[16], c1[16], cs0[16], cs1[16];
    #pragma unroll
    for (int i = 0; i < 16; ++i) { c0[i] = 0.f; c1[i] = 0.f; }

    // One 32-hidden chunk of one LSTM cell step. s is ALWAYS a literal at the
    // call site and cc a named array -> all private indexing constant-folds.
    auto lstm_chunk = [&](int rb, int wbuf, const unsigned short* base, int s,
                          float (&cc)[16]) {
        const int chunk = 2*wv + s;
        floatx4 acc0[8], acc1[8];
        #pragma unroll
        for (int nt = 0; nt < 8; ++nt) {
            acc0[nt] = (floatx4){0.f,0.f,0.f,0.f};
            acc1[nt] = (floatx4){0.f,0.f,0.f,0.f};
        }
        const unsigned short* bp = base + (size_t)chunk*CHELEM + lane*8;
        short8 bA[8], bB[8];
        #pragma unroll
        for (int nt = 0; nt < 8; ++nt) bA[nt] = *(const short8*)(bp + nt*512);
        #pragma unroll 1
        for (int kt = 0; kt < 16; kt += 2) {
            const unsigned short* p1 = bp + (kt+1)*4096;
            #pragma unroll
            for (int nt = 0; nt < 8; ++nt) bB[nt] = *(const short8*)(p1 + nt*512);
            short8 a0 = *(const short8*)&abuf[rb][l15][kt*32 + lq*8];
            short8 a1 = *(const short8*)&abuf[rb][16 + l15][kt*32 + lq*8];
            #pragma unroll
            for (int nt = 0; nt < 8; ++nt) {
                acc0[nt] = __builtin_amdgcn_mfma_f32_16x16x32_bf16(a0, bA[nt], acc0[nt], 0,0,0);
                acc1[nt] = __builtin_amdgcn_mfma_f32_16x16x32_bf16(a1, bA[nt], acc1[nt], 0,0,0);
            }
            const unsigned short* p2 = bp + (kt+2)*4096;
            #pragma unroll
            for (int nt = 0; nt < 8; ++nt) bA[nt] = *(const short8*)(p2 + nt*512);
            a0 = *(const short8*)&abuf[rb][l15][(kt+1)*32 + lq*8];
            a1 = *(const short8*)&abuf[rb][16 + l15][(kt+1)*32 + lq*8];
            #pragma unroll
            for (int nt = 0; nt < 8; ++nt) {
                acc0[nt] = __builtin_amdgcn_mfma_f32_16x16x32_bf16(a0, bB[nt], acc0[nt], 0,0,0);
                acc1[nt] = __builtin_amdgcn_mfma_f32_16x16x32_bf16(a1, bB[nt], acc1[nt], 0,0,0);
            }
        }
        {   // kt = 16 tail: bA holds kt=16 (loaded at kt=14 iteration) — BOTH accs use bA
            short8 a0 = *(const short8*)&abuf[rb][l15][16*32 + lq*8];
            short8 a1 = *(const short8*)&abuf[rb][16 + l15][16*32 + lq*8];
            #pragma unroll
            for (int nt = 0; nt < 8; ++nt) {
                acc0[nt] = __builtin_amdgcn_mfma_f32_16x16x32_bf16(a0, bA[nt], acc0[nt], 0,0,0);
                acc1[nt] = __builtin_amdgcn_mfma_f32_16x16x32_bf16(a1, bA[nt], acc1[nt], 0,0,0);
            }
        }
        // ntile pairs: 0..1=i, 2..3=f, 4..5=g, 6..7=o
        #pragma unroll
        for (int up = 0; up < 2; ++up)
            #pragma unroll
            for (int r = 0; r < 4; ++r) {
                {   // mf = 0
                    int ci = (up*2+0)*4 + r;
                    float cn = sigf(acc0[2+up][r])*cc[ci] + sigf(acc0[0+up][r])*tanh_(acc0[4+up][r]);
                    cc[ci] = cn;
                    float h = sigf(acc0[6+up][r])*tanh_(cn);
                    abuf[wbuf][lq*4 + r][chunk*32 + up*16 + l15] = f2bf(h);
                }
                {   // mf = 1
                    int ci = (up*2+1)*4 + r;
                    float cn = sigf(acc1[2+up][r])*cc[ci] + sigf(acc1[0+up][r])*tanh_(acc1[4+up][r]);
                    cc[ci] = cn;
                    float h = sigf(acc1[6+up][r])*tanh_(cn);
                    abuf[wbuf][16 + lq*4 + r][chunk*32 + up*16 + l15] = f2bf(h);
                }
            }
    };

    const unsigned short* wsp = wpack;
    const unsigned short* wpp = wpack + LSTRIDE;
    const unsigned short* wdp = wpack + 2*(size_t)LSTRIDE;

    // ---- speed encoder ----
    #pragma unroll 1
    for (int t = 0; t < 16; ++t) {
        int rb = t&1, wbuf = (t+1)&1;
        lstm_chunk(rb, wbuf, wsp, 0, c0);
        lstm_chunk(rb, wbuf, wsp, 1, c1);
        if (t < 15 && tid < 128) {
            int m = tid>>2, f3 = tid&3;
            abuf[wbuf][m][512+f3] = f2bf(speed[((size_t)(row0+m)*16 + t+1)*4 + f3]);
        }
        __syncthreads();
    }
    // save h_s -> hsave (LDS), c_s -> cs regs; reset c
    for (int i = tid; i < MTILE*64; i += NTHR) {
        int m = i>>6, cb = (i&63)*8;
        *(short8*)&hsave[m][cb] = *(const short8*)&abuf[0][m][cb];
    }
    #pragma unroll
    for (int i = 0; i < 16; ++i) { cs0[i]=c0[i]; c0[i]=0.f; cs1[i]=c1[i]; c1[i]=0.f; }
    __syncthreads();
    // zero buf0 h-region; load x_pos[0]
    for (int i = tid; i < MTILE*256; i += NTHR) {
        int m = i>>8, kk = i&255;
        ((unsigned*)&abuf[0][m][0])[kk] = 0u;
    }
    if (tid < 128) {
        int m = tid>>2, f3 = tid&3;
        abuf[0][m][512+f3] = f2bf(pos[((size_t)(row0+m)*16 + 0)*4 + f3]);
    }
    __syncthreads();

    // ---- pos encoder ----
    #pragma unroll 1
    for (int t = 0; t < 16; ++t) {
        int rb = t&1, wbuf = (t+1)&1;
        lstm_chunk(rb, wbuf, wpp, 0, c0);
        lstm_chunk(rb, wbuf, wpp, 1, c1);
        if (t < 15 && tid < 128) {
            int m = tid>>2, f3 = tid&3;
            abuf[wbuf][m][512+f3] = f2bf(pos[((size_t)(row0+m)*16 + t+1)*4 + f3]);
        }
        __syncthreads();
    }
    // h0 = ph + sh; c0 = pc + sc; last_pos0 = pos[:,15,:]
    #pragma unroll
    for (int i = 0; i < 16; ++i) { c0[i] += cs0[i]; c1[i] += cs1[i]; }
    for (int i = tid; i < MTILE*64; i += NTHR) {
        int m = i>>6, cb = (i&63)*8;
        short8 hv = *(const short8*)&abuf[0][m][cb];
        short8 sv = *(const short8*)&hsave[m][cb];
        short8 o;
        #pragma unroll
        for (int q = 0; q < 8; ++q)
            o[q] = (short)f2bf(bf2f((unsigned short)hv[q]) + bf2f((unsigned short)sv[q]));
        *(short8*)&abuf[0][m][cb] = o;
    }
    if (tid < 128) {
        int m = tid>>2, f3 = tid&3;
        abuf[0][m][512+f3] = f2bf(pos[((size_t)(row0+m)*16 + 15)*4 + f3]);
    }
    __syncthreads();

    // ---- decoder ----
    #pragma unroll 1
    for (int t = 0; t < 16; ++t) {
        int rb = t&1, wbuf = (t+1)&1;
        lstm_chunk(rb, wbuf, wdp, 0, c0);
        lstm_chunk(rb, wbuf, wdp, 1, c1);
        __syncthreads();
        {   // crossing partials: wave wv covers k-slice [wv*64, wv*64+64)
            int r = lane>>1, col = lane&1;
            const unsigned short* hp = &abuf[wbuf][r][wv*64];
            const float* wp = &smallw[col*512 + wv*64];
            float p = 0.f;
            #pragma unroll
            for (int k = 0; k < 64; ++k) p += bf2f(hp[k]) * wp[k];
            partial[wv*64 + lane] = p;
        }
        __syncthreads();
        if (wv == 0) {
            float p = 0.f;
            #pragma unroll
            for (int i = 0; i < 8; ++i) p += partial[i*64 + lane];
            int r = lane>>1, col = lane&1;
            p += smallw[1024+col];
            float cr = fmaxf(p, 0.f);
            float other = __shfl_xor(cr, 1, 64);
            float mx = fmaxf(cr, other);
            float e0 = ex2(LOG2E*(cr-mx)), e1 = ex2(LOG2E*(other-mx));
            out[((size_t)(row0+r))*32 + t*2 + col] = e0/(e0+e1);
            float c0v = col ? other : cr;
            float c1v = col ? cr : other;
            #pragma unroll
            for (int q = 0; q < 2; ++q) {
                int e = col*2 + q;
                float lp = fmaxf(c0v*smallw[1026+e*2] + c1v*smallw[1026+e*2+1] + smallw[1034+e], 0.f);
                abuf[wbuf][r][512+e] = f2bf(lp);
            }
        }
        __syncthreads();
    }
}

extern "C" void kernel_launch(void* const* d_in, const int* in_sizes, int n_in,
                              void* d_out, int out_size, void* d_ws, size_t ws_size,
                              hipStream_t stream)
{
    (void)in_sizes; (void)n_in; (void)out_size; (void)ws_size;
    const float* speed = (const float*)d_in[0];
    const float* pos   = (const float*)d_in[1];
    const float* Ws_ih = (const float*)d_in[2];
    const float* Ws_hh = (const float*)d_in[3];
    const float* bs_ih = (const float*)d_in[4];
    const float* bs_hh = (const float*)d_in[5];
    const float* Wp_ih = (const float*)d_in[6];
    const float* Wp_hh = (const float*)d_in[7];
    const float* bp_ih = (const float*)d_in[8];
    const float* bp_hh = (const float*)d_in[9];
    const float* Wd_ih = (const float*)d_in[10];
    const float* Wd_hh = (const float*)d_in[11];
    const float* bd_ih = (const float*)d_in[12];
    const float* bd_hh = (const float*)d_in[13];
    const float* W_fc  = (const float*)d_in[14];
    const float* b_fc  = (const float*)d_in[15];
    const float* W_emb = (const float*)d_in[16];
    const float* b_emb = (const float*)d_in[17];

    unsigned short* wp = (unsigned short*)d_ws;
    int gb = (LSTRIDE + 255) / 256;
    prepack<<<gb, 256, 0, stream>>>(Ws_ih, Ws_hh, bs_ih, bs_hh, wp);
    prepack<<<gb, 256, 0, stream>>>(Wp_ih, Wp_hh, bp_ih, bp_hh, wp + LSTRIDE);
    prepack<<<gb, 256, 0, stream>>>(Wd_ih, Wd_hh, bd_ih, bd_hh, wp + 2*(size_t)LSTRIDE);
    lstm_all<<<NBLK, NTHR, 0, stream>>>(speed, pos, wp, W_fc, b_fc, W_emb, b_emb, (float*)d_out);
}